// Round 11
// baseline (298.544 us; speedup 1.0000x reference)
//
#include <hip/hip_runtime.h>
#include <stdint.h>
#include <math.h>

// Algebra (validated R3-R7):
//   q = x0 @ Wq + bq ; r[h][d] = sum_c q[h*64+c] * Wk[d][h*64+c]
//   logits[h][n] = (r[h] . x[n]) / 8 ; p = softmax_n ; y[h] = sum_n p[h][n] x[n]
//   ctx[h*64+u] = sum_d y[h][d] Wv[d][h*64+u] + bv ; out = ctx @ Wo + bo
// R19: all single-block-per-CU variants pinned at 134-159us with every pipe
// <25% busy -> barrier convoys idle the whole CU. This round: split each bs
// across 2 blocks by head-group (heads hg*4..hg*4+3). 512 thr, ~28KB LDS ->
// TWO independent blocks per CU: barrier stall in one overlaps issue in the
// other. Cross-head out-projection moved to a second (proven) k-split GEMM.

__global__ __launch_bounds__(512, 4) void fused_half(
    const float* __restrict__ x,
    const float* __restrict__ Wq, const float* __restrict__ bq,
    const float* __restrict__ Wk,
    const float* __restrict__ Wv, const float* __restrict__ bv,
    float* __restrict__ ctx_ws) {
  const int bs = blockIdx.x >> 1;
  const int hg = blockIdx.x & 1;     // head group: global heads hg*4..hg*4+3
  const int t = threadIdx.x;
  const int w = t >> 6, lane = t & 63;
  const float* xb = x + (long)bs * 131072;  // x[bs][n][d], 256*512

  __shared__ __align__(16) float x0_s[512];
  __shared__ __align__(16) float q_s[256];       // our 4 heads' q
  __shared__ __align__(16) float r_s[4 * 512];
  __shared__ __align__(16) float red_s[7][256];
  __shared__ __align__(16) float y_sp[4][520];
  __shared__ __align__(16) float pt_s[2][4][16]; // parity-dbuf probabilities
  __shared__ float f_s[2][4];
  __shared__ float s_s[4];

  // ---- prologue: stage cls row; preload tile-0 logits rows (w, 8+w) ----
  if (t < 128) *(float4*)&x0_s[t * 4] = *(const float4*)&xb[t * 4];
  float4 c00 = *(const float4*)&xb[(long)w * 512 + lane * 8];
  float4 c01 = *(const float4*)&xb[(long)w * 512 + lane * 8 + 4];
  float4 c10 = *(const float4*)&xb[(long)(8 + w) * 512 + lane * 8];
  float4 c11 = *(const float4*)&xb[(long)(8 + w) * 512 + lane * 8 + 4];
  __syncthreads();

  // ---- P0: q[hg*256 + j] = x0 . Wq[:, hg*256+j] + bq (8-way k-split) ----
  {
    const int jj = t & 63;            // 64 float4 outputs = 256 cols
    const int kq = t >> 6;            // 0..7, 64 k's each
    const int j4 = hg * 256 + jj * 4;
    float4 a = make_float4(0.f, 0.f, 0.f, 0.f);
    const float* wp = Wq + (long)(kq * 64) * 512 + j4;
    const float* ap = &x0_s[kq * 64];
#pragma unroll 8
    for (int k = 0; k < 64; ++k) {
      float4 wv = *(const float4*)&wp[(long)k * 512];
      float av = ap[k];
      a.x += av * wv.x; a.y += av * wv.y; a.z += av * wv.z; a.w += av * wv.w;
    }
    if (kq > 0) *(float4*)&red_s[kq - 1][jj * 4] = a;
    __syncthreads();
    if (kq == 0) {
#pragma unroll
      for (int rr = 0; rr < 7; ++rr) {
        float4 b = *(const float4*)&red_s[rr][jj * 4];
        a.x += b.x; a.y += b.y; a.z += b.z; a.w += b.w;
      }
      float4 bb = *(const float4*)&bq[j4];
      a.x += bb.x; a.y += bb.y; a.z += bb.z; a.w += bb.w;
      *(float4*)&q_s[jj * 4] = a;   // local: q_s[c] = q[hg*256 + c]
    }
  }
  __syncthreads();

  // ---- P1: r[hl][d] = sum_c q_s[hl*64+c] * Wk[d][hg*256 + hl*64 + c] ----
  {
    const int d = t;                  // 0..511
    const float* wrow = Wk + (long)d * 512 + hg * 256;
#pragma unroll
    for (int hl = 0; hl < 4; ++hl) {
      const float* qp = &q_s[hl * 64];
      float racc = 0.f;
#pragma unroll
      for (int c4 = 0; c4 < 16; ++c4) {
        float4 wv = *(const float4*)&wrow[hl * 64 + c4 * 4];
        racc += qp[c4 * 4 + 0] * wv.x + qp[c4 * 4 + 1] * wv.y +
                qp[c4 * 4 + 2] * wv.z + qp[c4 * 4 + 3] * wv.w;
      }
      r_s[hl * 512 + d] = racc;
    }
  }
  __syncthreads();

  // ---- rv: every wave loads all 4 local heads (32 regs) ----
  float rv[4][8];
#pragma unroll
  for (int hl = 0; hl < 4; ++hl) {
    float4 a = *(const float4*)&r_s[hl * 512 + lane * 8];
    float4 b = *(const float4*)&r_s[hl * 512 + lane * 8 + 4];
    rv[hl][0] = a.x; rv[hl][1] = a.y; rv[hl][2] = a.z; rv[hl][3] = a.w;
    rv[hl][4] = b.x; rv[hl][5] = b.y; rv[hl][6] = b.z; rv[hl][7] = b.w;
  }

  // ---- online-softmax state ----
  float accy[4] = {0.f, 0.f, 0.f, 0.f};
  float m_h = -INFINITY, s_h = 0.f;   // wave w<4 tracks local head w

  for (int tile = 0; tile < 16; ++tile) {
    const int b = tile & 1;

    // logits: wave w does rows w and 8+w, all 4 local heads
    {
      float acc[4];
      // pass 0: row w
#pragma unroll
      for (int hl = 0; hl < 4; ++hl)
        acc[hl] = c00.x * rv[hl][0] + c00.y * rv[hl][1] + c00.z * rv[hl][2] + c00.w * rv[hl][3]
                + c01.x * rv[hl][4] + c01.y * rv[hl][5] + c01.z * rv[hl][6] + c01.w * rv[hl][7];
#pragma unroll
      for (int j = 0; j < 2; ++j) {
        float v = (lane & 2) ? acc[j] : acc[j + 2];
        float tt = __shfl_xor(v, 2);
        acc[j] = ((lane & 2) ? acc[j + 2] : acc[j]) + tt;
      }
      {
        float v = (lane & 1) ? acc[0] : acc[1];
        float tt = __shfl_xor(v, 1);
        acc[0] = ((lane & 1) ? acc[1] : acc[0]) + tt;
      }
      acc[0] += __shfl_xor(acc[0], 4);
      acc[0] += __shfl_xor(acc[0], 8);
      acc[0] += __shfl_xor(acc[0], 16);
      acc[0] += __shfl_xor(acc[0], 32);
      if (lane < 4) pt_s[b][lane][w] = acc[0] * 0.125f;
      // pass 1: row 8+w
#pragma unroll
      for (int hl = 0; hl < 4; ++hl)
        acc[hl] = c10.x * rv[hl][0] + c10.y * rv[hl][1] + c10.z * rv[hl][2] + c10.w * rv[hl][3]
                + c11.x * rv[hl][4] + c11.y * rv[hl][5] + c11.z * rv[hl][6] + c11.w * rv[hl][7];
#pragma unroll
      for (int j = 0; j < 2; ++j) {
        float v = (lane & 2) ? acc[j] : acc[j + 2];
        float tt = __shfl_xor(v, 2);
        acc[j] = ((lane & 2) ? acc[j + 2] : acc[j]) + tt;
      }
      {
        float v = (lane & 1) ? acc[0] : acc[1];
        float tt = __shfl_xor(v, 1);
        acc[0] = ((lane & 1) ? acc[1] : acc[0]) + tt;
      }
      acc[0] += __shfl_xor(acc[0], 4);
      acc[0] += __shfl_xor(acc[0], 8);
      acc[0] += __shfl_xor(acc[0], 16);
      acc[0] += __shfl_xor(acc[0], 32);
      if (lane < 4) pt_s[b][lane][8 + w] = acc[0] * 0.125f;
    }
    __syncthreads();   // B1: logits visible

    // online-softmax: wave w<4 owns local head w; lanes 0..15 hold the tile
    if (w < 4) {
      float l = (lane < 16) ? pt_s[b][w][lane] : -3.0e38f;
      float tm = l;
#pragma unroll
      for (int o = 8; o; o >>= 1) tm = fmaxf(tm, __shfl_xor(tm, o));
      float m_new = fmaxf(m_h, tm);
      float e = __expf(l - m_new);
      float ts = e;
#pragma unroll
      for (int o = 8; o; o >>= 1) ts += __shfl_xor(ts, o);
      float f = __expf(m_h - m_new);  // tile 0: exp(-inf)=0
      s_h = s_h * f + ts;
      m_h = m_new;
      if (lane == 0) f_s[b][w] = f;
      if (lane < 16) pt_s[b][w][lane] = e;
    }
    __syncthreads();   // B2: e + f ready

    // prefetch next tile's logits rows (no barrier between issue and use)
    float4 n00, n01, n10, n11;
    if (tile < 15) {
      const float* nx = xb + (long)(tile + 1) * 8192;
      n00 = *(const float4*)&nx[(long)w * 512 + lane * 8];
      n01 = *(const float4*)&nx[(long)w * 512 + lane * 8 + 4];
      n10 = *(const float4*)&nx[(long)(8 + w) * 512 + lane * 8];
      n11 = *(const float4*)&nx[(long)(8 + w) * 512 + lane * 8 + 4];
    }

    // y accumulate: thread owns d=t, all 16 n's of the tile, 4 heads
    {
#pragma unroll
      for (int hl = 0; hl < 4; ++hl) accy[hl] *= f_s[b][hl];
      const float* xg = xb + (long)tile * 8192 + t;
#pragma unroll
      for (int n4 = 0; n4 < 4; ++n4) {
        float xv0 = xg[(long)(n4 * 4 + 0) * 512];
        float xv1 = xg[(long)(n4 * 4 + 1) * 512];
        float xv2 = xg[(long)(n4 * 4 + 2) * 512];
        float xv3 = xg[(long)(n4 * 4 + 3) * 512];
#pragma unroll
        for (int hl = 0; hl < 4; ++hl) {
          float4 p4 = *(const float4*)&pt_s[b][hl][n4 * 4];
          accy[hl] += p4.x * xv0 + p4.y * xv1 + p4.z * xv2 + p4.w * xv3;
        }
      }
    }
    if (tile < 15) { c00 = n00; c01 = n01; c10 = n10; c11 = n11; }
    // no end barrier: next iter writes parity b^1; pt_s[b] next written at
    // logits(t+2), which is behind B1(t+1) -> ordered after this y phase.
  }

  // ---- finalize y ----
  if (w < 4 && lane == 0) s_s[w] = s_h;
  __syncthreads();
#pragma unroll
  for (int hl = 0; hl < 4; ++hl)
    y_sp[hl][t] = accy[hl] * (1.f / s_s[hl]);
  __syncthreads();

  // ---- P5: ctx[hg*256 + o] = sum_d y[h(o)][d] Wv[d][o] + bv -> workspace ----
  {
    const int jj = t & 63;            // 64 float4 outputs
    const int kq = t >> 6;            // 8-way k-split
    const int o4 = hg * 256 + jj * 4;
    const int hl = jj >> 4;           // local head of these 4 outputs
    float4 a = make_float4(0.f, 0.f, 0.f, 0.f);
    const float* wp = Wv + (long)(kq * 64) * 512 + o4;
    const float* yp = &y_sp[hl][kq * 64];
#pragma unroll 8
    for (int k = 0; k < 64; ++k) {
      float4 wv = *(const float4*)&wp[(long)k * 512];
      float yv = yp[k];
      a.x += yv * wv.x; a.y += yv * wv.y; a.z += yv * wv.z; a.w += yv * wv.w;
    }
    if (kq > 0) *(float4*)&red_s[kq - 1][jj * 4] = a;
    __syncthreads();
    if (kq == 0) {
#pragma unroll
      for (int rr = 0; rr < 7; ++rr) {
        float4 b = *(const float4*)&red_s[rr][jj * 4];
        a.x += b.x; a.y += b.y; a.z += b.z; a.w += b.w;
      }
      float4 bb = *(const float4*)&bv[o4];
      a.x += bb.x; a.y += bb.y; a.z += bb.z; a.w += bb.w;
      *(float4*)&ctx_ws[(long)bs * 512 + o4] = a;
    }
  }
}

// ---- kernel 2: out = ctx @ Wo + bo (proven k-split gemm from R0-R8) ----
__global__ __launch_bounds__(256) void gemm_ks_kernel(
    const float* __restrict__ A, const float* __restrict__ W,
    const float* __restrict__ bias, float* __restrict__ C) {
  __shared__ float a_s[4][512];
  __shared__ float red_s[3][4][64];
  const int rt = blockIdx.x, jt = blockIdx.y, t = threadIdx.x;
  const int w = t >> 6, lane = t & 63;

#pragma unroll
  for (int l = 0; l < 2; ++l) {
    int flat4 = t + l * 256;
    int arow = flat4 >> 7;
    int k4 = (flat4 & 127) * 4;
    float4 v = *(const float4*)&A[(long)(rt * 4 + arow) * 512 + k4];
    a_s[arow][k4] = v.x; a_s[arow][k4 + 1] = v.y;
    a_s[arow][k4 + 2] = v.z; a_s[arow][k4 + 3] = v.w;
  }
  __syncthreads();

  const int j = jt * 64 + lane;
  float acc0 = 0.f, acc1 = 0.f, acc2 = 0.f, acc3 = 0.f;
  const float* wp = W + (long)(w * 128) * 512 + j;
  const float* ap = &a_s[0][w * 128];
#pragma unroll 8
  for (int k = 0; k < 128; ++k) {
    float wv = wp[(long)k * 512];
    acc0 += ap[k] * wv;
    acc1 += ap[512 + k] * wv;
    acc2 += ap[1024 + k] * wv;
    acc3 += ap[1536 + k] * wv;
  }
  if (w > 0) {
    red_s[w - 1][0][lane] = acc0;
    red_s[w - 1][1][lane] = acc1;
    red_s[w - 1][2][lane] = acc2;
    red_s[w - 1][3][lane] = acc3;
  }
  __syncthreads();
  if (w == 0) {
#pragma unroll
    for (int rr = 0; rr < 3; ++rr) {
      acc0 += red_s[rr][0][lane];
      acc1 += red_s[rr][1][lane];
      acc2 += red_s[rr][2][lane];
      acc3 += red_s[rr][3][lane];
    }
    const float b = bias[j];
    C[(long)(rt * 4 + 0) * 512 + j] = acc0 + b;
    C[(long)(rt * 4 + 1) * 512 + j] = acc1 + b;
    C[(long)(rt * 4 + 2) * 512 + j] = acc2 + b;
    C[(long)(rt * 4 + 3) * 512 + j] = acc3 + b;
  }
}

extern "C" void kernel_launch(void* const* d_in, const int* in_sizes, int n_in,
                              void* d_out, int out_size, void* d_ws, size_t ws_size,
                              hipStream_t stream) {
  (void)in_sizes; (void)n_in; (void)out_size; (void)ws_size;
  const float* x  = (const float*)d_in[0];
  const float* Wq = (const float*)d_in[1];
  const float* bq = (const float*)d_in[2];
  const float* Wk = (const float*)d_in[3];
  // d_in[4] = bk: softmax-invariant, unused
  const float* Wv = (const float*)d_in[5];
  const float* bv = (const float*)d_in[6];
  const float* Wo = (const float*)d_in[7];
  const float* bo = (const float*)d_in[8];
  float* out = (float*)d_out;
  float* ctx_ws = (float*)d_ws;   // 256*512 floats = 0.5 MiB

  fused_half<<<512, 512, 0, stream>>>(x, Wq, bq, Wk, Wv, bv, ctx_ws);
  gemm_ks_kernel<<<dim3(64, 8), 256, 0, stream>>>(ctx_ws, Wo, bo, out);
}

// Round 12
// 264.703 us; speedup vs baseline: 1.1278x; 1.1278x over previous
//
#include <hip/hip_runtime.h>
#include <stdint.h>
#include <math.h>

// Algebra (validated R3-R7): only the cls token queries.
//   q = x0 @ Wq + bq ; r_h = q_h @ Wk_h^T ; logits = (r . x_n)/8
//   p = softmax ; y_h = sum_n p_h[n] x[n] ; ctx_h = y_h @ Wv_h + bv ; out = ctx @ Wo + bo
// R20: cross-round accounting shows R1's 5-launch pipeline (262.7 bench) had
// ~117us kernel time -- better than ALL fused variants (134-159us). Its attn
// has only 3 barriers total (full-row logits in 8KB LDS, no tiling/online-SM)
// and 2 blocks/CU co-residency at VGPR=64. Restored verbatim, with one fix:
// logits split 2-waves-per-rows x 4-heads (rv[4][8], R13-proven reduce) so
// live regs fit the 64-VGPR cap WITHOUT spills (R1 spilled rv[8][8]).

// ---------------- gemm k-split body (proven R8) ----------------
__device__ __forceinline__ void gemm_ks_body(
    const float* __restrict__ A, long a_row_stride, int a_col_off_mult,
    const float* __restrict__ W, const float* __restrict__ bias,
    float* __restrict__ C, int rt, int jt, int t,
    float (*a_s)[512], float (*red_s)[4][64]) {
  const int w = t >> 6, lane = t & 63;

#pragma unroll
  for (int l = 0; l < 2; ++l) {
    int flat4 = t + l * 256;
    int arow = flat4 >> 7;
    int k4 = (flat4 & 127) * 4;
    float4 v = *(const float4*)&A[(long)(rt * 4 + arow) * a_row_stride +
                                  (long)jt * a_col_off_mult + k4];
    a_s[arow][k4] = v.x; a_s[arow][k4 + 1] = v.y;
    a_s[arow][k4 + 2] = v.z; a_s[arow][k4 + 3] = v.w;
  }
  __syncthreads();

  const int j = jt * 64 + lane;
  float acc0 = 0.f, acc1 = 0.f, acc2 = 0.f, acc3 = 0.f;
  const float* wp = W + (long)(w * 128) * 512 + j;
  const float* ap = &a_s[0][w * 128];
#pragma unroll 8
  for (int k = 0; k < 128; ++k) {
    float wv = wp[(long)k * 512];
    acc0 += ap[k] * wv;
    acc1 += ap[512 + k] * wv;
    acc2 += ap[1024 + k] * wv;
    acc3 += ap[1536 + k] * wv;
  }
  if (w > 0) {
    red_s[w - 1][0][lane] = acc0;
    red_s[w - 1][1][lane] = acc1;
    red_s[w - 1][2][lane] = acc2;
    red_s[w - 1][3][lane] = acc3;
  }
  __syncthreads();
  if (w == 0) {
#pragma unroll
    for (int rr = 0; rr < 3; ++rr) {
      acc0 += red_s[rr][0][lane];
      acc1 += red_s[rr][1][lane];
      acc2 += red_s[rr][2][lane];
      acc3 += red_s[rr][3][lane];
    }
    const float b = bias[j];
    C[(long)(rt * 4 + 0) * 512 + j] = acc0 + b;
    C[(long)(rt * 4 + 1) * 512 + j] = acc1 + b;
    C[(long)(rt * 4 + 2) * 512 + j] = acc2 + b;
    C[(long)(rt * 4 + 3) * 512 + j] = acc3 + b;
  }
}

// ---------------- K1: merged transpose (blocks 0-255) + q gemm (256-767) ----
__global__ __launch_bounds__(256) void prep_kernel(
    const float* __restrict__ x, const float* __restrict__ Wq,
    const float* __restrict__ bq, const float* __restrict__ Wk,
    float* __restrict__ WkT, float* __restrict__ q) {
  __shared__ float a_s[4][512];
  __shared__ float red_s[3][4][64];
  const int t = threadIdx.x;

  if (blockIdx.x < 256) {
    float (*tile)[64] = (float(*)[64])&a_s[0][0];   // 32x33 fits in 8KB
    const int j0 = (blockIdx.x & 15) * 32;
    const int c0 = (blockIdx.x >> 4) * 32;
    {
      const int row = t >> 3;
      const int c4 = (t & 7) * 4;
      float4 v = *(const float4*)&Wk[(long)(j0 + row) * 512 + c0 + c4];
      float* tr = &tile[0][0] + row * 33;
      tr[c4] = v.x; tr[c4 + 1] = v.y; tr[c4 + 2] = v.z; tr[c4 + 3] = v.w;
    }
    __syncthreads();
    {
      const int row = t >> 3;
      const int j4 = (t & 7) * 4;
      const float* tb = &tile[0][0];
      float4 v = make_float4(tb[j4 * 33 + row], tb[(j4 + 1) * 33 + row],
                             tb[(j4 + 2) * 33 + row], tb[(j4 + 3) * 33 + row]);
      *(float4*)&WkT[(long)(c0 + row) * 512 + j0 + j4] = v;
    }
  } else {
    const int bid = blockIdx.x - 256;
    const int rt = bid & 63;
    const int jt = bid >> 6;
    gemm_ks_body(x, 131072L, 0, Wq, bq, q, rt, jt, t, a_s, red_s);
  }
}

// ---------------- standalone k-split gemm (ctx, out) ----------------
__global__ __launch_bounds__(256) void gemm_ks_kernel(
    const float* __restrict__ A, long a_row_stride, int a_col_off_mult,
    const float* __restrict__ W, const float* __restrict__ bias,
    float* __restrict__ C) {
  __shared__ float a_s[4][512];
  __shared__ float red_s[3][4][64];
  gemm_ks_body(A, a_row_stride, a_col_off_mult, W, bias, C,
               blockIdx.x, blockIdx.y, threadIdx.x, a_s, red_s);
}

// ---------------- r[256][4096]: r[s][h*512+jp] = q_h . WkT cols ----------------
__global__ __launch_bounds__(256) void r_kernel(
    const float* __restrict__ q, const float* __restrict__ WkT,
    float* __restrict__ r_all) {
  const int rt = blockIdx.x;
  const int h = blockIdx.y;
  const int t = threadIdx.x;
  __shared__ float q_s[4][64];

  {
    int row = t >> 6, c = t & 63;
    q_s[row][c] = q[(long)(rt * 4 + row) * 512 + h * 64 + c];
  }
  __syncthreads();

  const int jp4 = (t & 127) * 4;
  const int rh = t >> 7;
  float4 acc0 = make_float4(0.f, 0.f, 0.f, 0.f);
  float4 acc1 = make_float4(0.f, 0.f, 0.f, 0.f);
#pragma unroll 8
  for (int c = 0; c < 64; ++c) {
    float4 w4 = *(const float4*)&WkT[(long)(h * 64 + c) * 512 + jp4];
    float q0 = q_s[rh * 2][c], q1 = q_s[rh * 2 + 1][c];
    acc0.x += q0 * w4.x; acc0.y += q0 * w4.y; acc0.z += q0 * w4.z; acc0.w += q0 * w4.w;
    acc1.x += q1 * w4.x; acc1.y += q1 * w4.y; acc1.z += q1 * w4.z; acc1.w += q1 * w4.w;
  }
  *(float4*)&r_all[(long)(rt * 4 + rh * 2) * 4096 + h * 512 + jp4] = acc0;
  *(float4*)&r_all[(long)(rt * 4 + rh * 2 + 1) * 4096 + h * 512 + jp4] = acc1;
}

// ---------------- fused logits + softmax + y : one block per bs --------------
// 1024 thr, 3 barriers TOTAL. Logits: wave pair (rw=w>>1 rows, hg=w&1 heads),
// rv[4][8]=32 regs -> no spill at the 64-VGPR cap -> 2 blocks/CU co-resident.
__global__ __launch_bounds__(1024) void attn_kernel(
    const float* __restrict__ x, const float* __restrict__ r_all,
    float* __restrict__ Y) {
  const int bs = blockIdx.x;
  const int t = threadIdx.x;
  const int w = t >> 6, lane = t & 63;
  const float* xb = x + (long)bs * 131072;
  __shared__ float p_s[8][256];   // logits, then probabilities (8 KB)
  __shared__ float yp[8][512];    // pass-2 partials from half 1 (16 KB)

  const int hg = w & 1;     // head group: heads hg*4 .. hg*4+3
  const int rw = w >> 1;    // row group: rows rw*32 .. rw*32+31

  // ---- load r fragments for our 4 heads (32 regs) ----
  float rv[4][8];
  const float* rb = r_all + (long)bs * 4096 + lane * 8;
#pragma unroll
  for (int hi = 0; hi < 4; ++hi) {
    const int h = hg * 4 + hi;
    float4 a = *(const float4*)&rb[h * 512];
    float4 b = *(const float4*)&rb[h * 512 + 4];
    rv[hi][0] = a.x; rv[hi][1] = a.y; rv[hi][2] = a.z; rv[hi][3] = a.w;
    rv[hi][4] = b.x; rv[hi][5] = b.y; rv[hi][6] = b.z; rv[hi][7] = b.w;
  }

  // ---- pass 1: logits, 32 serial rows per wave, 4 heads each ----
#pragma unroll 4
  for (int i = 0; i < 32; ++i) {
    const int n = rw * 32 + i;
    const float* xr = xb + (long)n * 512 + lane * 8;
    float4 xa = *(const float4*)xr;
    float4 xb4 = *(const float4*)(xr + 4);
    float acc[4];
#pragma unroll
    for (int hi = 0; hi < 4; ++hi)
      acc[hi] = xa.x * rv[hi][0] + xa.y * rv[hi][1] + xa.z * rv[hi][2] + xa.w * rv[hi][3]
              + xb4.x * rv[hi][4] + xb4.y * rv[hi][5] + xb4.z * rv[hi][6] + xb4.w * rv[hi][7];
#pragma unroll
    for (int j = 0; j < 2; ++j) {
      float v = (lane & 2) ? acc[j] : acc[j + 2];
      float tt = __shfl_xor(v, 2);
      acc[j] = ((lane & 2) ? acc[j + 2] : acc[j]) + tt;
    }
    {
      float v = (lane & 1) ? acc[0] : acc[1];
      float tt = __shfl_xor(v, 1);
      acc[0] = ((lane & 1) ? acc[1] : acc[0]) + tt;
    }
    acc[0] += __shfl_xor(acc[0], 4);
    acc[0] += __shfl_xor(acc[0], 8);
    acc[0] += __shfl_xor(acc[0], 16);
    acc[0] += __shfl_xor(acc[0], 32);
    if (lane < 4) p_s[hg * 4 + lane][n] = acc[0] * 0.125f;
  }
  __syncthreads();

  // ---- softmax: wave w < 8 handles head w (R1 verbatim) ----
  if (w < 8) {
    float4 lv = *(const float4*)&p_s[w][lane * 4];
    float m = fmaxf(fmaxf(lv.x, lv.y), fmaxf(lv.z, lv.w));
    for (int o = 32; o; o >>= 1) m = fmaxf(m, __shfl_xor(m, o));
    float e0 = __expf(lv.x - m), e1 = __expf(lv.y - m);
    float e2 = __expf(lv.z - m), e3 = __expf(lv.w - m);
    float s = e0 + e1 + e2 + e3;
    for (int o = 32; o; o >>= 1) s += __shfl_xor(s, o);
    const float inv = 1.f / s;
    *(float4*)&p_s[w][lane * 4] = make_float4(e0 * inv, e1 * inv, e2 * inv, e3 * inv);
  }
  __syncthreads();

  // ---- pass 2: y_h[d] = sum_n p[h][n] x[n][d], n split in halves ----
  const int d = t & 511;
  const int half = t >> 9;
  float acc[8] = {};
  const float* xb2 = xb + ((long)half * 128) * 512 + d;
#pragma unroll 8
  for (int n = 0; n < 128; ++n) {
    float xv = xb2[(long)n * 512];
#pragma unroll
    for (int h = 0; h < 8; ++h)
      acc[h] += p_s[h][half * 128 + n] * xv;
  }
  if (half == 1) {
#pragma unroll
    for (int h = 0; h < 8; ++h) yp[h][d] = acc[h];
  }
  __syncthreads();
  if (half == 0) {
#pragma unroll
    for (int h = 0; h < 8; ++h)
      Y[(long)bs * 4096 + h * 512 + d] = acc[h] + yp[h][d];
  }
}

extern "C" void kernel_launch(void* const* d_in, const int* in_sizes, int n_in,
                              void* d_out, int out_size, void* d_ws, size_t ws_size,
                              hipStream_t stream) {
  (void)in_sizes; (void)n_in; (void)out_size; (void)ws_size;
  const float* x  = (const float*)d_in[0];
  const float* Wq = (const float*)d_in[1];
  const float* bq = (const float*)d_in[2];
  const float* Wk = (const float*)d_in[3];
  const float* bk = (const float*)d_in[4];  (void)bk;  // softmax-invariant
  const float* Wv = (const float*)d_in[5];
  const float* bv = (const float*)d_in[6];
  const float* Wo = (const float*)d_in[7];
  const float* bo = (const float*)d_in[8];
  float* out = (float*)d_out;

  float* WkT = (float*)d_ws;       // 512*512  = 1 MiB
  float* q   = WkT + 262144;       // 256*512  = 0.5 MiB
  float* r   = q + 131072;         // 256*4096 = 4 MiB
  float* Y   = r + 1048576;        // 256*4096 = 4 MiB
  float* ctx = Y + 1048576;        // 256*512  = 0.5 MiB

  prep_kernel<<<768, 256, 0, stream>>>(x, Wq, bq, Wk, WkT, q);
  r_kernel<<<dim3(64, 8), 256, 0, stream>>>(q, WkT, r);
  attn_kernel<<<256, 1024, 0, stream>>>(x, r, Y);
  gemm_ks_kernel<<<dim3(64, 8), 256, 0, stream>>>(Y, 4096L, 512, Wv, bv, ctx);
  gemm_ks_kernel<<<dim3(64, 8), 256, 0, stream>>>(ctx, 512L, 0, Wo, bo, out);
}